// Round 1
// baseline (225.888 us; speedup 1.0000x reference)
//
#include <hip/hip_runtime.h>
#include <hip/hip_bf16.h>

// y[i, d] = x[i, d] * A_diag[d] + B[d]
// N = 262144, D = 512, all fp32. Pure streaming FMA -> HBM-bound.
// float4 vectorization: D/4 = 128 float4 columns per row.

#define D4 128  // D / 4

__global__ __launch_bounds__(256) void diag_affine_kernel(
    const float4* __restrict__ x,
    const float*  __restrict__ A,
    const float*  __restrict__ B,
    float4* __restrict__ out,
    int n4)
{
    // Stage A and B into LDS as float4 (128 each, 2 KB + 2 KB).
    __shared__ float4 sA[D4];
    __shared__ float4 sB[D4];
    for (int i = threadIdx.x; i < D4; i += blockDim.x) {
        sA[i] = reinterpret_cast<const float4*>(A)[i];
        sB[i] = reinterpret_cast<const float4*>(B)[i];
    }
    __syncthreads();

    const int stride = gridDim.x * blockDim.x;
    for (int i = blockIdx.x * blockDim.x + threadIdx.x; i < n4; i += stride) {
        const int j = i & (D4 - 1);   // float4-column index within the row
        float4 v = x[i];
        float4 a = sA[j];
        float4 b = sB[j];
        float4 r;
        r.x = fmaf(v.x, a.x, b.x);
        r.y = fmaf(v.y, a.y, b.y);
        r.z = fmaf(v.z, a.z, b.z);
        r.w = fmaf(v.w, a.w, b.w);
        out[i] = r;
    }
}

extern "C" void kernel_launch(void* const* d_in, const int* in_sizes, int n_in,
                              void* d_out, int out_size, void* d_ws, size_t ws_size,
                              hipStream_t stream) {
    const float* x = (const float*)d_in[0];
    const float* A = (const float*)d_in[1];
    const float* B = (const float*)d_in[2];
    float* out = (float*)d_out;

    const int n4 = out_size / 4;            // 33,554,432 float4 elements
    const int block = 256;
    const int grid = 2048;                  // 8 blocks/CU x 256 CUs, grid-stride

    diag_affine_kernel<<<grid, block, 0, stream>>>(
        reinterpret_cast<const float4*>(x), A, B,
        reinterpret_cast<float4*>(out), n4);
}